// Round 3
// baseline (304.073 us; speedup 1.0000x reference)
//
#include <hip/hip_runtime.h>
#include <hip/hip_bf16.h>
#include <stdint.h>

typedef __attribute__((ext_vector_type(4))) float f32x4;
typedef __attribute__((ext_vector_type(8))) short short8;
typedef unsigned int u32;
typedef unsigned short ushort_t;

#define L_DIM 2048
#define B_DIM 32
#define D_DIM 512
#define M_DIM (L_DIM * B_DIM)       // 65536
#define N_DIM (3 * D_DIM)           // 1536
#define K_DIM D_DIM                 // 512
#define BD    (B_DIM * D_DIM)       // 16384
#define PLANE ((size_t)M_DIM * D_DIM)  // 33554432 elems per U plane
#define CHUNK 32
#define NCHUNK (L_DIM / CHUNK)      // 64

// ---------- helpers ----------
__device__ inline ushort_t f2bf(float f) {
    uint32_t u = __float_as_uint(f);
    u += 0x7FFFu + ((u >> 16) & 1u);   // RNE
    return (ushort_t)(u >> 16);
}
__device__ inline float b2f(ushort_t h) {
    return __uint_as_float(((uint32_t)h) << 16);
}
__device__ inline void gll16(const ushort_t* g, ushort_t* l) {
    __builtin_amdgcn_global_load_lds(
        (const __attribute__((address_space(1))) u32*)g,
        (__attribute__((address_space(3))) u32*)l,
        16, 0, 0);
}
__device__ inline void gll4(const ushort_t* g, ushort_t* l) {
    __builtin_amdgcn_global_load_lds(
        (const __attribute__((address_space(1))) u32*)g,
        (__attribute__((address_space(3))) u32*)l,
        4, 0, 0);
}

// ---------- kernel 1: x (f32) -> xb (bf16) ----------
__global__ void k_convert_x(const float4* __restrict__ x, ushort4* __restrict__ xb) {
    int i = blockIdx.x * blockDim.x + threadIdx.x;
    int stride = gridDim.x * blockDim.x;
    const int n4 = M_DIM * D_DIM / 4;   // 8388608
    for (; i < n4; i += stride) {
        float4 v = x[i];
        ushort4 o;
        o.x = f2bf(v.x); o.y = f2bf(v.y); o.z = f2bf(v.z); o.w = f2bf(v.w);
        xb[i] = o;
    }
}

// ---------- kernel 2: weight (D,3D) f32 -> wt [N][K] bf16, gate-deinterleaved ----------
__global__ void k_prep_w(const float* __restrict__ w, ushort_t* __restrict__ wt) {
    int idx = blockIdx.x * blockDim.x + threadIdx.x;
    if (idx >= N_DIM * K_DIM) return;
    int k = idx & 511;
    int n = idx >> 9;
    int dcol = (n & 511) * 3 + (n >> 9);
    wt[idx] = f2bf(w[(size_t)k * N_DIM + dcol]);
}

// ---------- kernel 3: GEMM (unchanged from round 1, verified) ----------
__global__ __launch_bounds__(256) void k_gemm(
    const ushort_t* __restrict__ Ag,   // [M,K] bf16
    const ushort_t* __restrict__ Wt,   // [N,K] bf16
    const float*    __restrict__ bias, // [2D]
    ushort_t*       __restrict__ U)    // 3 planes of [M,D] bf16
{
    __shared__ ushort_t As[128 * 64];
    __shared__ ushort_t Bs[128 * 64];
    const int tid  = threadIdx.x;
    const int lane = tid & 63;
    const int w    = tid >> 6;
    const int wm   = w >> 1, wn = w & 1;
    const int bn0  = blockIdx.x * 128;   // N offset
    const int bm0  = blockIdx.y * 128;   // M offset

    f32x4 acc[4][4] = {};

    for (int kt = 0; kt < K_DIM / 64; ++kt) {
        if (kt) __syncthreads();
#pragma unroll
        for (int it = 0; it < 4; ++it) {
            int c   = it * 256 + tid;
            int row = c >> 3;
            int cin = (c & 7) ^ (row & 7);
            const ushort_t* ga = Ag + (size_t)(bm0 + row) * K_DIM + kt * 64 + cin * 8;
            const ushort_t* gb = Wt + (size_t)(bn0 + row) * K_DIM + kt * 64 + cin * 8;
            int chunkbase = it * 256 + w * 64;   // wave-uniform
            gll16(ga, As + chunkbase * 8);
            gll16(gb, Bs + chunkbase * 8);
        }
        __syncthreads();
#pragma unroll
        for (int kk = 0; kk < 2; ++kk) {
            short8 af[4], bfr[4];
#pragma unroll
            for (int m = 0; m < 4; ++m) {
                int row  = wm * 64 + m * 16 + (lane & 15);
                int byte = (row * 128 + kk * 64 + ((lane >> 4) * 16)) ^ ((row & 7) << 4);
                af[m] = *(const short8*)((const char*)As + byte);
            }
#pragma unroll
            for (int n = 0; n < 4; ++n) {
                int row  = wn * 64 + n * 16 + (lane & 15);
                int byte = (row * 128 + kk * 64 + ((lane >> 4) * 16)) ^ ((row & 7) << 4);
                bfr[n] = *(const short8*)((const char*)Bs + byte);
            }
#pragma unroll
            for (int m = 0; m < 4; ++m)
#pragma unroll
                for (int n = 0; n < 4; ++n)
                    acc[m][n] = __builtin_amdgcn_mfma_f32_16x16x32_bf16(
                        af[m], bfr[n], acc[m][n], 0, 0, 0);
        }
    }

    const int g  = bn0 >> 9;               // plane (block fully inside one plane)
    const int db = (bn0 & 511) + wn * 64;  // d base in plane
    ushort_t* Up = U + (size_t)g * PLANE;
#pragma unroll
    for (int n = 0; n < 4; ++n) {
        int col = db + n * 16 + (lane & 15);
        float ba = 0.f;
        if (g) ba = bias[(g - 1) * 512 + col];
#pragma unroll
        for (int m = 0; m < 4; ++m) {
            int row0 = bm0 + wm * 64 + m * 16 + ((lane >> 4) * 4);
#pragma unroll
            for (int q = 0; q < 4; ++q) {
                Up[(size_t)(row0 + q) * D_DIM + col] = f2bf(acc[m][n][q] + ba);
            }
        }
    }
}

// ---------- kernel 4: producer/consumer sequential scan ----------
// wave 0: streams u0,u1,u2,x planes into double-buffered LDS ring via
//         global_load_lds (independent loads -> full MLP, latency-immune)
// wave 1: serial recurrence out of LDS, coalesced h stores
__global__ __launch_bounds__(128) void k_scan(
    const ushort_t* __restrict__ U,    // 3 planes [t*32+b][d]
    const ushort_t* __restrict__ xb,   // [t*32+b][d]
    const float*    __restrict__ wc,   // weight_c [2D]
    const float*    __restrict__ cin,  // c_init [B,D]
    float*          __restrict__ out)  // h [L,B,D] f32, then c_last [B,D]
{
    __shared__ ushort_t ring[4][2][CHUNK][64];   // 32 KiB

    const int tid  = threadIdx.x;
    const int lane = tid & 63;
    const int wid  = tid >> 6;
    const int cb   = blockIdx.x * 64;            // chain base

    // ---- producer state (wave 0) ----
    const int half = lane >> 5;                  // which step of the 2-step pair
    const int coff = (lane & 31) * 2;            // 2 chains per lane (4B)
    const ushort_t* s0 = U + cb + coff;
    const ushort_t* s1 = U + PLANE + cb + coff;
    const ushort_t* s2 = U + 2 * PLANE + cb + coff;
    const ushort_t* s3 = xb + cb + coff;

    // ---- consumer state (wave 1) ----
    const int chain = cb + lane;
    const int d     = chain & 511;
    float fw = 0.f, rw = 0.f, c = 0.f;
    if (wid == 1) { fw = wc[d]; rw = wc[512 + d]; c = cin[chain]; }
    float* ho = out + chain;

#define PRODUCE(CK, NB)                                                        \
    do {                                                                       \
        const size_t t0_ = (size_t)(CK) * CHUNK + half;                        \
        _Pragma("unroll")                                                      \
        for (int j = 0; j < 16; ++j) {                                         \
            gll4(s0 + (t0_ + 2 * j) * BD, &ring[0][NB][2 * j][0]);             \
            gll4(s1 + (t0_ + 2 * j) * BD, &ring[1][NB][2 * j][0]);             \
            gll4(s2 + (t0_ + 2 * j) * BD, &ring[2][NB][2 * j][0]);             \
            gll4(s3 + (t0_ + 2 * j) * BD, &ring[3][NB][2 * j][0]);             \
        }                                                                      \
    } while (0)

#define LG(P, BUF, g0)                                                         \
    {                                                                          \
        _Pragma("unroll")                                                      \
        for (int s = 0; s < 8; ++s) {                                          \
            P##0[s] = ring[0][BUF][(g0) + s][lane];                            \
            P##1[s] = ring[1][BUF][(g0) + s][lane];                            \
            P##2[s] = ring[2][BUF][(g0) + s][lane];                            \
            P##x[s] = ring[3][BUF][(g0) + s][lane];                            \
        }                                                                      \
    }

#define CG(P, tb, g0)                                                          \
    {                                                                          \
        _Pragma("unroll")                                                      \
        for (int s = 0; s < 8; ++s) {                                          \
            float u0 = b2f(P##0[s]), u1 = b2f(P##1[s]);                        \
            float u2 = b2f(P##2[s]), xf = b2f(P##x[s]);                        \
            float f = __builtin_amdgcn_rcpf(1.f + __expf(-(u1 + c * fw)));     \
            float r = __builtin_amdgcn_rcpf(1.f + __expf(-(u2 + c * rw)));     \
            c = u0 + (c - u0) * f;                                             \
            ho[(size_t)((tb) + (g0) + s) * BD] = xf + (c - xf) * r;            \
        }                                                                      \
    }

    if (wid == 0) PRODUCE(0, 0);
    __syncthreads();

    for (int ck = 0; ck < NCHUNK; ++ck) {
        if (wid == 0) {
            if (ck + 1 < NCHUNK) {
                const int nb = (ck + 1) & 1;
                PRODUCE(ck + 1, nb);
            }
        } else {
            const int buf = ck & 1;
            const int tb  = ck * CHUNK;
            ushort_t A0[8], A1[8], A2[8], Ax[8];
            ushort_t B0[8], B1[8], B2[8], Bx[8];
            LG(A, buf, 0);
            LG(B, buf, 8);
            CG(A, tb, 0);
            LG(A, buf, 16);
            CG(B, tb, 8);
            LG(B, buf, 24);
            CG(A, tb, 16);
            CG(B, tb, 24);
        }
        __syncthreads();
    }

    if (wid == 1) out[(size_t)L_DIM * BD + chain] = c;
}

// ---------- launch ----------
extern "C" void kernel_launch(void* const* d_in, const int* in_sizes, int n_in,
                              void* d_out, int out_size, void* d_ws, size_t ws_size,
                              hipStream_t stream) {
    const float* x      = (const float*)d_in[0];
    const float* weight = (const float*)d_in[1];
    const float* wc     = (const float*)d_in[2];
    const float* bias   = (const float*)d_in[3];
    const float* cinit  = (const float*)d_in[4];
    float* out = (float*)d_out;

    // ws layout (bf16 elems): xb[33554432] | U0|U1|U2 [3*33554432] | wt[786432]
    ushort_t* ws = (ushort_t*)d_ws;
    ushort_t* xb = ws;
    ushort_t* U  = ws + PLANE;           // 3 contiguous planes
    ushort_t* wt = ws + 4 * PLANE;

    k_convert_x<<<4096, 256, 0, stream>>>((const float4*)x, (ushort4*)xb);
    k_prep_w<<<(N_DIM * K_DIM) / 256, 256, 0, stream>>>(weight, wt);
    dim3 grid(N_DIM / 128, M_DIM / 128);   // (12, 512)
    k_gemm<<<grid, 256, 0, stream>>>(xb, wt, bias, U);
    k_scan<<<BD / 64, 128, 0, stream>>>(U, xb, wc, cinit, out);
}

// Round 4
// 302.273 us; speedup vs baseline: 1.0060x; 1.0060x over previous
//
#include <hip/hip_runtime.h>
#include <hip/hip_bf16.h>
#include <stdint.h>

typedef __attribute__((ext_vector_type(4))) float f32x4;
typedef __attribute__((ext_vector_type(8))) short short8;
typedef unsigned int u32;
typedef unsigned short ushort_t;

#define L_DIM 2048
#define B_DIM 32
#define D_DIM 512
#define M_DIM (L_DIM * B_DIM)       // 65536
#define N_DIM (3 * D_DIM)           // 1536
#define K_DIM D_DIM                 // 512
#define BD    (B_DIM * D_DIM)       // 16384
#define PLANE ((size_t)M_DIM * D_DIM)  // 33554432 elems per U plane
#define CHUNK 32
#define NCHUNK (L_DIM / CHUNK)      // 64

// ---------- helpers ----------
__device__ inline ushort_t f2bf(float f) {
    uint32_t u = __float_as_uint(f);
    u += 0x7FFFu + ((u >> 16) & 1u);   // RNE
    return (ushort_t)(u >> 16);
}
__device__ inline float b2f(ushort_t h) {
    return __uint_as_float(((uint32_t)h) << 16);
}
__device__ inline void gll16(const ushort_t* g, ushort_t* l) {
    __builtin_amdgcn_global_load_lds(
        (const __attribute__((address_space(1))) u32*)g,
        (__attribute__((address_space(3))) u32*)l,
        16, 0, 0);
}

// ---------- kernel 1: x (f32) -> xb (bf16) ----------
__global__ void k_convert_x(const float4* __restrict__ x, ushort4* __restrict__ xb) {
    int i = blockIdx.x * blockDim.x + threadIdx.x;
    int stride = gridDim.x * blockDim.x;
    const int n4 = M_DIM * D_DIM / 4;   // 8388608
    for (; i < n4; i += stride) {
        float4 v = x[i];
        ushort4 o;
        o.x = f2bf(v.x); o.y = f2bf(v.y); o.z = f2bf(v.z); o.w = f2bf(v.w);
        xb[i] = o;
    }
}

// ---------- kernel 2: weight (D,3D) f32 -> wt [N][K] bf16, gate-deinterleaved ----------
__global__ void k_prep_w(const float* __restrict__ w, ushort_t* __restrict__ wt) {
    int idx = blockIdx.x * blockDim.x + threadIdx.x;
    if (idx >= N_DIM * K_DIM) return;
    int k = idx & 511;
    int n = idx >> 9;
    int dcol = (n & 511) * 3 + (n >> 9);
    wt[idx] = f2bf(w[(size_t)k * N_DIM + dcol]);
}

// ---------- kernel 3: GEMM with XCD-chunked swizzle ----------
// 1-D grid 6144; remap so each XCD owns contiguous block ranges -> all 12
// N-tiles of an M-strip co-resident on one XCD -> A panel L2-resident.
__global__ __launch_bounds__(256) void k_gemm(
    const ushort_t* __restrict__ Ag,   // [M,K] bf16
    const ushort_t* __restrict__ Wt,   // [N,K] bf16
    const float*    __restrict__ bias, // [2D]
    ushort_t*       __restrict__ U)    // 3 planes of [M,D] bf16
{
    __shared__ ushort_t As[128 * 64];
    __shared__ ushort_t Bs[128 * 64];
    const int tid  = threadIdx.x;
    const int lane = tid & 63;
    const int w    = tid >> 6;
    const int wm   = w >> 1, wn = w & 1;

    // XCD-chunked swizzle: 6144 blocks, 8 XCDs, 768 per XCD (bijective).
    const int i   = blockIdx.x;
    const int nb  = (i & 7) * 768 + (i >> 3);
    const int bx  = nb % 12;             // N tile (innermost -> A reuse)
    const int by  = nb / 12;             // M strip
    const int bn0 = bx * 128;
    const int bm0 = by * 128;

    f32x4 acc[4][4] = {};

    for (int kt = 0; kt < K_DIM / 64; ++kt) {
        if (kt) __syncthreads();
#pragma unroll
        for (int it = 0; it < 4; ++it) {
            int c   = it * 256 + tid;
            int row = c >> 3;
            int cin = (c & 7) ^ (row & 7);
            const ushort_t* ga = Ag + (size_t)(bm0 + row) * K_DIM + kt * 64 + cin * 8;
            const ushort_t* gb = Wt + (size_t)(bn0 + row) * K_DIM + kt * 64 + cin * 8;
            int chunkbase = it * 256 + w * 64;   // wave-uniform
            gll16(ga, As + chunkbase * 8);
            gll16(gb, Bs + chunkbase * 8);
        }
        __syncthreads();
#pragma unroll
        for (int kk = 0; kk < 2; ++kk) {
            short8 af[4], bfr[4];
#pragma unroll
            for (int m = 0; m < 4; ++m) {
                int row  = wm * 64 + m * 16 + (lane & 15);
                int byte = (row * 128 + kk * 64 + ((lane >> 4) * 16)) ^ ((row & 7) << 4);
                af[m] = *(const short8*)((const char*)As + byte);
            }
#pragma unroll
            for (int n = 0; n < 4; ++n) {
                int row  = wn * 64 + n * 16 + (lane & 15);
                int byte = (row * 128 + kk * 64 + ((lane >> 4) * 16)) ^ ((row & 7) << 4);
                bfr[n] = *(const short8*)((const char*)Bs + byte);
            }
#pragma unroll
            for (int m = 0; m < 4; ++m)
#pragma unroll
                for (int n = 0; n < 4; ++n)
                    acc[m][n] = __builtin_amdgcn_mfma_f32_16x16x32_bf16(
                        af[m], bfr[n], acc[m][n], 0, 0, 0);
        }
    }

    const int g  = bn0 >> 9;               // plane (block fully inside one plane)
    const int db = (bn0 & 511) + wn * 64;  // d base in plane
    ushort_t* Up = U + (size_t)g * PLANE;
#pragma unroll
    for (int n = 0; n < 4; ++n) {
        int col = db + n * 16 + (lane & 15);
        float ba = 0.f;
        if (g) ba = bias[(g - 1) * 512 + col];
#pragma unroll
        for (int m = 0; m < 4; ++m) {
            int row0 = bm0 + wm * 64 + m * 16 + ((lane >> 4) * 4);
#pragma unroll
            for (int q = 0; q < 4; ++q) {
                Up[(size_t)(row0 + q) * D_DIM + col] = f2bf(acc[m][n][q] + ba);
            }
        }
    }
}

// ---------- kernel 4: producer/consumer sequential scan ----------
// wave 0: streams u0,u1,u2,x planes into double-buffered LDS ring via
//         width-16 global_load_lds (4 instrs/plane/chunk, 1KB each)
// wave 1: serial recurrence out of LDS, coalesced h stores
__global__ __launch_bounds__(128) void k_scan(
    const ushort_t* __restrict__ U,    // 3 planes [t*32+b][d]
    const ushort_t* __restrict__ xb,   // [t*32+b][d]
    const float*    __restrict__ wc,   // weight_c [2D]
    const float*    __restrict__ cin,  // c_init [B,D]
    float*          __restrict__ out)  // h [L,B,D] f32, then c_last [B,D]
{
    __shared__ ushort_t ring[4][2][CHUNK][64];   // 32 KiB

    const int tid  = threadIdx.x;
    const int lane = tid & 63;
    const int wid  = tid >> 6;
    const int cb   = blockIdx.x * 64;            // chain base

    // ---- producer state (wave 0) ----
    // gll16: lane l covers step srow = l>>3 (of each 8-step group), chains (l&7)*8..+7
    const int srow = lane >> 3;
    const int scol = (lane & 7) * 8;
    const ushort_t* s0 = U + cb + scol;
    const ushort_t* s1 = U + PLANE + cb + scol;
    const ushort_t* s2 = U + 2 * PLANE + cb + scol;
    const ushort_t* s3 = xb + cb + scol;

    // ---- consumer state (wave 1) ----
    const int chain = cb + lane;
    const int d     = chain & 511;
    float fw = 0.f, rw = 0.f, c = 0.f;
    if (wid == 1) { fw = wc[d]; rw = wc[512 + d]; c = cin[chain]; }
    float* ho = out + chain;

#define PRODUCE(CK, NB)                                                        \
    do {                                                                       \
        const size_t t0_ = (size_t)(CK) * CHUNK + srow;                        \
        _Pragma("unroll")                                                      \
        for (int q = 0; q < 4; ++q) {                                          \
            gll16(s0 + (t0_ + q * 8) * BD, &ring[0][NB][q * 8][0]);            \
            gll16(s1 + (t0_ + q * 8) * BD, &ring[1][NB][q * 8][0]);            \
            gll16(s2 + (t0_ + q * 8) * BD, &ring[2][NB][q * 8][0]);            \
            gll16(s3 + (t0_ + q * 8) * BD, &ring[3][NB][q * 8][0]);            \
        }                                                                      \
    } while (0)

#define LG(P, BUF, g0)                                                         \
    {                                                                          \
        _Pragma("unroll")                                                      \
        for (int s = 0; s < 8; ++s) {                                          \
            P##0[s] = ring[0][BUF][(g0) + s][lane];                            \
            P##1[s] = ring[1][BUF][(g0) + s][lane];                            \
            P##2[s] = ring[2][BUF][(g0) + s][lane];                            \
            P##x[s] = ring[3][BUF][(g0) + s][lane];                            \
        }                                                                      \
    }

#define CG(P, tb, g0)                                                          \
    {                                                                          \
        _Pragma("unroll")                                                      \
        for (int s = 0; s < 8; ++s) {                                          \
            float u0 = b2f(P##0[s]), u1 = b2f(P##1[s]);                        \
            float u2 = b2f(P##2[s]), xf = b2f(P##x[s]);                        \
            float f = __builtin_amdgcn_rcpf(1.f + __expf(-(u1 + c * fw)));     \
            float r = __builtin_amdgcn_rcpf(1.f + __expf(-(u2 + c * rw)));     \
            c = u0 + (c - u0) * f;                                             \
            ho[(size_t)((tb) + (g0) + s) * BD] = xf + (c - xf) * r;            \
        }                                                                      \
    }

    if (wid == 0) PRODUCE(0, 0);
    __syncthreads();

    for (int ck = 0; ck < NCHUNK; ++ck) {
        if (wid == 0) {
            if (ck + 1 < NCHUNK) {
                const int nb = (ck + 1) & 1;
                PRODUCE(ck + 1, nb);
            }
        } else {
            const int buf = ck & 1;
            const int tb  = ck * CHUNK;
            ushort_t A0[8], A1[8], A2[8], Ax[8];
            ushort_t B0[8], B1[8], B2[8], Bx[8];
            LG(A, buf, 0);
            LG(B, buf, 8);
            CG(A, tb, 0);
            LG(A, buf, 16);
            CG(B, tb, 8);
            LG(B, buf, 24);
            CG(A, tb, 16);
            CG(B, tb, 24);
        }
        __syncthreads();
    }

    if (wid == 1) out[(size_t)L_DIM * BD + chain] = c;
}

// ---------- launch ----------
extern "C" void kernel_launch(void* const* d_in, const int* in_sizes, int n_in,
                              void* d_out, int out_size, void* d_ws, size_t ws_size,
                              hipStream_t stream) {
    const float* x      = (const float*)d_in[0];
    const float* weight = (const float*)d_in[1];
    const float* wc     = (const float*)d_in[2];
    const float* bias   = (const float*)d_in[3];
    const float* cinit  = (const float*)d_in[4];
    float* out = (float*)d_out;

    // ws layout (bf16 elems): xb[33554432] | U0|U1|U2 [3*33554432] | wt[786432]
    ushort_t* ws = (ushort_t*)d_ws;
    ushort_t* xb = ws;
    ushort_t* U  = ws + PLANE;           // 3 contiguous planes
    ushort_t* wt = ws + 4 * PLANE;

    k_convert_x<<<4096, 256, 0, stream>>>((const float4*)x, (ushort4*)xb);
    k_prep_w<<<(N_DIM * K_DIM) / 256, 256, 0, stream>>>(weight, wt);
    k_gemm<<<6144, 256, 0, stream>>>(xb, wt, bias, U);
    k_scan<<<BD / 64, 128, 0, stream>>>(U, xb, wc, cinit, out);
}

// Round 5
// 298.503 us; speedup vs baseline: 1.0187x; 1.0126x over previous
//
#include <hip/hip_runtime.h>
#include <hip/hip_bf16.h>
#include <stdint.h>

typedef __attribute__((ext_vector_type(4))) float f32x4;
typedef __attribute__((ext_vector_type(8))) short short8;
typedef unsigned int u32;
typedef unsigned short ushort_t;

#define L_DIM 2048
#define B_DIM 32
#define D_DIM 512
#define M_DIM (L_DIM * B_DIM)       // 65536
#define N_DIM (3 * D_DIM)           // 1536
#define K_DIM D_DIM                 // 512
#define BD    (B_DIM * D_DIM)       // 16384
#define PLANE ((size_t)M_DIM * D_DIM)  // 33554432 elems per U plane
#define CHUNK 32
#define NCHUNK (L_DIM / CHUNK)      // 64

// ---------- helpers ----------
__device__ inline ushort_t f2bf(float f) {
    uint32_t u = __float_as_uint(f);
    u += 0x7FFFu + ((u >> 16) & 1u);   // RNE
    return (ushort_t)(u >> 16);
}
__device__ inline float b2f(ushort_t h) {
    return __uint_as_float(((uint32_t)h) << 16);
}
__device__ inline void gll16(const ushort_t* g, ushort_t* l) {
    __builtin_amdgcn_global_load_lds(
        (const __attribute__((address_space(1))) u32*)g,
        (__attribute__((address_space(3))) u32*)l,
        16, 0, 0);
}

// ---------- kernel 1: x (f32) -> xb (bf16) ----------
__global__ void k_convert_x(const float4* __restrict__ x, ushort4* __restrict__ xb) {
    int i = blockIdx.x * blockDim.x + threadIdx.x;
    int stride = gridDim.x * blockDim.x;
    const int n4 = M_DIM * D_DIM / 4;   // 8388608
    for (; i < n4; i += stride) {
        float4 v = x[i];
        ushort4 o;
        o.x = f2bf(v.x); o.y = f2bf(v.y); o.z = f2bf(v.z); o.w = f2bf(v.w);
        xb[i] = o;
    }
}

// ---------- kernel 2: weight (D,3D) f32 -> wt [N][K] bf16, gate-deinterleaved ----------
__global__ void k_prep_w(const float* __restrict__ w, ushort_t* __restrict__ wt) {
    int idx = blockIdx.x * blockDim.x + threadIdx.x;
    if (idx >= N_DIM * K_DIM) return;
    int k = idx & 511;
    int n = idx >> 9;
    int dcol = (n & 511) * 3 + (n >> 9);
    wt[idx] = f2bf(w[(size_t)k * N_DIM + dcol]);
}

// ---------- kernel 3: 256x256 8-phase GEMM (T1+T2+T3+T4+T5) ----------
// 8 waves (2M x 4N), BK=64, 128 KiB LDS dbuf, counted vmcnt(8), setprio MFMA.
// Fragment row maps: A row = m*32 + wr*16 + lane15  (mh=0 <-> rows 0-127)
//                    B row = n*64 + wc*16 + lane15  (nh=0 <-> rows 0-127)
// so each staged region's last ds_read precedes its overwrite-issue phase.
__global__ __launch_bounds__(512, 2) void k_gemm8(
    const ushort_t* __restrict__ Ag,   // [M,K] bf16
    const ushort_t* __restrict__ Wt,   // [N,K] bf16
    const float*    __restrict__ bias, // [2D]
    ushort_t*       __restrict__ U)    // 3 planes of [M,D] bf16
{
    __shared__ ushort_t As[2][256 * 64];   // 64 KB
    __shared__ ushort_t Bs[2][256 * 64];   // 64 KB
    const int tid  = threadIdx.x;
    const int lane = tid & 63;
    const int wid  = tid >> 6;      // 0..7
    const int wr   = wid >> 2;      // 0..1 (M)
    const int wc   = wid & 3;       // 0..3 (N)

    // XCD-chunked swizzle: 1536 blocks, 8 XCDs, 192/XCD; bx innermost for A reuse
    const int i   = blockIdx.x;
    const int nb  = (i & 7) * 192 + (i >> 3);
    const int bx  = nb % 6;
    const int by  = nb / 6;
    const int bn0 = bx * 256;
    const int bm0 = by * 256;

    // staging per-thread invariants: round r covers rows r*64 + (tid>>3),
    // chunk-in-row (tid&7) XOR'd by (row&7) = ((tid>>3)&7)  (rule #21 source-side)
    const int scin = (tid & 7) ^ ((tid >> 3) & 7);
    const ushort_t* pA = Ag + (size_t)(bm0 + (tid >> 3)) * K_DIM + scin * 8;
    const ushort_t* pB = Wt + (size_t)(bn0 + (tid >> 3)) * K_DIM + scin * 8;

    f32x4 acc[8][4] = {};
    int kt2;

#define BAR()   __builtin_amdgcn_s_barrier()
#define PRIO1() __builtin_amdgcn_s_setprio(1)
#define PRIO0() __builtin_amdgcn_s_setprio(0)
#define STG_A(r) gll16(pA + (size_t)(r) * 64 * K_DIM + (size_t)kt2 * 64, \
                       Asb + (r) * 4096 + wid * 512)
#define STG_B(r) gll16(pB + (size_t)(r) * 64 * K_DIM + (size_t)kt2 * 64, \
                       Bsb + (r) * 4096 + wid * 512)

#define READ_A(MH)                                                            \
    _Pragma("unroll")                                                         \
    for (int mm = 0; mm < 4; ++mm)                                            \
        _Pragma("unroll")                                                     \
        for (int kk = 0; kk < 2; ++kk) {                                      \
            int rowA  = ((MH) * 4 + mm) * 32 + wr * 16 + (lane & 15);         \
            int byteA = (rowA * 128 + kk * 64 + ((lane >> 4) * 16))           \
                        ^ ((rowA & 7) << 4);                                  \
            af[mm][kk] = *(const short8*)((const char*)Asb + byteA);          \
        }

#define READ_B(NH)                                                            \
    _Pragma("unroll")                                                         \
    for (int nn = 0; nn < 2; ++nn)                                            \
        _Pragma("unroll")                                                     \
        for (int kk = 0; kk < 2; ++kk) {                                      \
            int rowB  = ((NH) * 2 + nn) * 64 + wc * 16 + (lane & 15);         \
            int byteB = (rowB * 128 + kk * 64 + ((lane >> 4) * 16))           \
                        ^ ((rowB & 7) << 4);                                  \
            bf[(NH) * 2 + nn][kk] = *(const short8*)((const char*)Bsb + byteB);\
        }

#define MFMAQ(MH, NH)                                                         \
    _Pragma("unroll")                                                         \
    for (int mm = 0; mm < 4; ++mm)                                            \
        _Pragma("unroll")                                                     \
        for (int nn = 0; nn < 2; ++nn)                                        \
            _Pragma("unroll")                                                 \
            for (int kk = 0; kk < 2; ++kk)                                    \
                acc[(MH) * 4 + mm][(NH) * 2 + nn] =                           \
                    __builtin_amdgcn_mfma_f32_16x16x32_bf16(                  \
                        af[mm][kk], bf[(NH) * 2 + nn][kk],                    \
                        acc[(MH) * 4 + mm][(NH) * 2 + nn], 0, 0, 0);

#define TILE(BUF, DO_STG, ENDW)                                               \
    {                                                                         \
        ushort_t* Asb = &As[BUF][0];                                          \
        ushort_t* Bsb = &Bs[BUF][0];                                          \
        short8 af[4][2], bf[4][2];                                            \
        /* phase 0: (mh=0, nh=0) */                                           \
        READ_A(0);                                                            \
        READ_B(0);                                                            \
        BAR();                                                                \
        PRIO1(); MFMAQ(0, 0); PRIO0();                                       \
        BAR();                                                                \
        /* phase 1: (mh=0, nh=1) */                                           \
        READ_B(1);                                                            \
        if (DO_STG) { STG_A(0); STG_A(1); }                                   \
        BAR();                                                                \
        PRIO1(); MFMAQ(0, 1); PRIO0();                                       \
        BAR();                                                                \
        /* phase 2: (mh=1, nh=0) */                                           \
        READ_A(1);                                                            \
        if (DO_STG) { STG_B(0); STG_B(1); }                                   \
        BAR();                                                                \
        PRIO1(); MFMAQ(1, 0); PRIO0();                                       \
        BAR();                                                                \
        /* phase 3: (mh=1, nh=1) */                                           \
        if (DO_STG) { STG_B(2); STG_B(3); STG_A(2); STG_A(3); }               \
        BAR();                                                                \
        PRIO1(); MFMAQ(1, 1); PRIO0();                                       \
        if ((ENDW) == 8)      asm volatile("s_waitcnt vmcnt(8)" ::: "memory");\
        else if ((ENDW) == 0) asm volatile("s_waitcnt vmcnt(0)" ::: "memory");\
        BAR();                                                                \
    }

    // prologue: fully stage K-tiles 0 and 1 (8 gll rounds each)
    {
        ushort_t* Asb = &As[0][0]; ushort_t* Bsb = &Bs[0][0]; kt2 = 0;
        STG_A(0); STG_B(0); STG_A(1); STG_B(1);
        STG_A(2); STG_B(2); STG_A(3); STG_B(3);
    }
    {
        ushort_t* Asb = &As[1][0]; ushort_t* Bsb = &Bs[1][0]; kt2 = 1;
        STG_A(0); STG_B(0); STG_A(1); STG_B(1);
        STG_A(2); STG_B(2); STG_A(3); STG_B(3);
    }
    asm volatile("s_waitcnt vmcnt(8)" ::: "memory");   // K-tile 0 landed
    BAR();

    // main pipeline: 8 K-tiles, prefetch depth 2, counted vmcnt(8)
    kt2 = 2; TILE(0, 1, 8);    // kt=0
    kt2 = 3; TILE(1, 1, 8);    // kt=1
    kt2 = 4; TILE(0, 1, 8);    // kt=2
    kt2 = 5; TILE(1, 1, 8);    // kt=3
    kt2 = 6; TILE(0, 1, 8);    // kt=4
    kt2 = 7; TILE(1, 1, 8);    // kt=5
    TILE(0, 0, 0);             // kt=6 (drain kt7 loads)
    TILE(1, 0, -1);            // kt=7

#undef TILE
#undef MFMAQ
#undef READ_A
#undef READ_B
#undef STG_A
#undef STG_B
#undef BAR
#undef PRIO1
#undef PRIO0

    // epilogue: C/D layout col=lane&15, row=(lane>>4)*4+q (m89-verified)
    const int g = bn0 >> 9;
    ushort_t* Up = U + (size_t)g * PLANE;
#pragma unroll
    for (int n = 0; n < 4; ++n) {
        int col = (bn0 & 511) + n * 64 + wc * 16 + (lane & 15);
        float ba = 0.f;
        if (g) ba = bias[(g - 1) * 512 + col];
#pragma unroll
        for (int m = 0; m < 8; ++m) {
            int row0 = bm0 + m * 32 + wr * 16 + ((lane >> 4) * 4);
#pragma unroll
            for (int q = 0; q < 4; ++q) {
                Up[(size_t)(row0 + q) * D_DIM + col] = f2bf(acc[m][n][q] + ba);
            }
        }
    }
}

// ---------- kernel 4: producer/consumer sequential scan (unchanged) ----------
__global__ __launch_bounds__(128) void k_scan(
    const ushort_t* __restrict__ U,    // 3 planes [t*32+b][d]
    const ushort_t* __restrict__ xb,   // [t*32+b][d]
    const float*    __restrict__ wc,   // weight_c [2D]
    const float*    __restrict__ cin,  // c_init [B,D]
    float*          __restrict__ out)  // h [L,B,D] f32, then c_last [B,D]
{
    __shared__ ushort_t ring[4][2][CHUNK][64];   // 32 KiB

    const int tid  = threadIdx.x;
    const int lane = tid & 63;
    const int wid  = tid >> 6;
    const int cb   = blockIdx.x * 64;            // chain base

    const int srow = lane >> 3;
    const int scol = (lane & 7) * 8;
    const ushort_t* s0 = U + cb + scol;
    const ushort_t* s1 = U + PLANE + cb + scol;
    const ushort_t* s2 = U + 2 * PLANE + cb + scol;
    const ushort_t* s3 = xb + cb + scol;

    const int chain = cb + lane;
    const int d     = chain & 511;
    float fw = 0.f, rw = 0.f, c = 0.f;
    if (wid == 1) { fw = wc[d]; rw = wc[512 + d]; c = cin[chain]; }
    float* ho = out + chain;

#define PRODUCE(CK, NB)                                                        \
    do {                                                                       \
        const size_t t0_ = (size_t)(CK) * CHUNK + srow;                        \
        _Pragma("unroll")                                                      \
        for (int q = 0; q < 4; ++q) {                                          \
            gll16(s0 + (t0_ + q * 8) * BD, &ring[0][NB][q * 8][0]);            \
            gll16(s1 + (t0_ + q * 8) * BD, &ring[1][NB][q * 8][0]);            \
            gll16(s2 + (t0_ + q * 8) * BD, &ring[2][NB][q * 8][0]);            \
            gll16(s3 + (t0_ + q * 8) * BD, &ring[3][NB][q * 8][0]);            \
        }                                                                      \
    } while (0)

#define LG(P, BUF, g0)                                                         \
    {                                                                          \
        _Pragma("unroll")                                                      \
        for (int s = 0; s < 8; ++s) {                                          \
            P##0[s] = ring[0][BUF][(g0) + s][lane];                            \
            P##1[s] = ring[1][BUF][(g0) + s][lane];                            \
            P##2[s] = ring[2][BUF][(g0) + s][lane];                            \
            P##x[s] = ring[3][BUF][(g0) + s][lane];                            \
        }                                                                      \
    }

#define CG(P, tb, g0)                                                          \
    {                                                                          \
        _Pragma("unroll")                                                      \
        for (int s = 0; s < 8; ++s) {                                          \
            float u0 = b2f(P##0[s]), u1 = b2f(P##1[s]);                        \
            float u2 = b2f(P##2[s]), xf = b2f(P##x[s]);                        \
            float f = __builtin_amdgcn_rcpf(1.f + __expf(-(u1 + c * fw)));     \
            float r = __builtin_amdgcn_rcpf(1.f + __expf(-(u2 + c * rw)));     \
            c = u0 + (c - u0) * f;                                             \
            ho[(size_t)((tb) + (g0) + s) * BD] = xf + (c - xf) * r;            \
        }                                                                      \
    }

    if (wid == 0) PRODUCE(0, 0);
    __syncthreads();

    for (int ck = 0; ck < NCHUNK; ++ck) {
        if (wid == 0) {
            if (ck + 1 < NCHUNK) {
                const int nb = (ck + 1) & 1;
                PRODUCE(ck + 1, nb);
            }
        } else {
            const int buf = ck & 1;
            const int tb  = ck * CHUNK;
            ushort_t A0[8], A1[8], A2[8], Ax[8];
            ushort_t B0[8], B1[8], B2[8], Bx[8];
            LG(A, buf, 0);
            LG(B, buf, 8);
            CG(A, tb, 0);
            LG(A, buf, 16);
            CG(B, tb, 8);
            LG(B, buf, 24);
            CG(A, tb, 16);
            CG(B, tb, 24);
        }
        __syncthreads();
    }

    if (wid == 1) out[(size_t)L_DIM * BD + chain] = c;
}

// ---------- launch ----------
extern "C" void kernel_launch(void* const* d_in, const int* in_sizes, int n_in,
                              void* d_out, int out_size, void* d_ws, size_t ws_size,
                              hipStream_t stream) {
    const float* x      = (const float*)d_in[0];
    const float* weight = (const float*)d_in[1];
    const float* wc     = (const float*)d_in[2];
    const float* bias   = (const float*)d_in[3];
    const float* cinit  = (const float*)d_in[4];
    float* out = (float*)d_out;

    // ws layout (bf16 elems): xb[33554432] | U0|U1|U2 [3*33554432] | wt[786432]
    ushort_t* ws = (ushort_t*)d_ws;
    ushort_t* xb = ws;
    ushort_t* U  = ws + PLANE;           // 3 contiguous planes
    ushort_t* wt = ws + 4 * PLANE;

    k_convert_x<<<4096, 256, 0, stream>>>((const float4*)x, (ushort4*)xb);
    k_prep_w<<<(N_DIM * K_DIM) / 256, 256, 0, stream>>>(weight, wt);
    k_gemm8<<<1536, 512, 0, stream>>>(xb, wt, bias, U);
    k_scan<<<BD / 64, 128, 0, stream>>>(U, xb, wc, cinit, out);
}